// Round 4
// baseline (873.053 us; speedup 1.0000x reference)
//
#include <hip/hip_runtime.h>
#include <stdint.h>

typedef unsigned short u16;
typedef unsigned int   u32;

// N = 160000, K = 16, C_IN = 64, C1 = 32, C_MID = 16, C2 = 64, C_OUT = 128
// Inputs: float32 (runtime probe retained as insurance). Outputs: float32.
// Comparison happens in bf16 space harness-side; we compute/store f32.

__device__ __forceinline__ float bf2f(u16 h) {
  return __uint_as_float(((u32)h) << 16);
}
__device__ __forceinline__ float lrelu(float x) { return x > 0.f ? x : 0.1f * x; }

// dtype-adaptive scalar load of float-typed input tensor
__device__ __forceinline__ float ldf(const void* p, size_t i, bool bf) {
  return bf ? bf2f(((const u16*)p)[i]) : ((const float*)p)[i];
}
__device__ __forceinline__ bool probe_bf16(const void* g) {
  // g_u1 is all ones. bf16 pair -> 0x3F803F80 ; f32 1.0f -> 0x3F800000
  return ((*(const u32*)g) & 0xFFFFu) == 0x3F80u;
}

// ---------------------------------------------------------------------------
// K1: feats_x = lrelu(feats @ (W_u1 * g) + b)   [N,64] -> [N,32], f32 out
// ---------------------------------------------------------------------------
__global__ __launch_bounds__(256) void k1_unary(
    const void* __restrict__ feats, const void* __restrict__ W,
    const void* __restrict__ g, const void* __restrict__ b,
    float* __restrict__ fx, int Npts)
{
  __shared__ float sW[64 * 32];
  __shared__ float sb[32];
  __shared__ float sf[8][64];
  bool bf = probe_bf16(g);
  int tid = threadIdx.x;
  for (int e = tid; e < 2048; e += 256) sW[e] = ldf(W, e, bf) * ldf(g, e & 31, bf);
  if (tid < 32) sb[tid] = ldf(b, tid, bf);
  int n0 = blockIdx.x * 8;
  for (int e = tid; e < 512; e += 256) {
    int p = e >> 6, i = e & 63;
    int n = n0 + p;
    sf[p][i] = (n < Npts) ? ldf(feats, (size_t)n * 64 + i, bf) : 0.f;
  }
  __syncthreads();
  int p = tid >> 5, c = tid & 31;
  int n = n0 + p;
  if (n < Npts) {
    float acc = sb[c];
#pragma unroll
    for (int i = 0; i < 64; ++i) acc += sf[p][i] * sW[i * 32 + c];
    fx[(size_t)n * 32 + c] = lrelu(acc);
  }
}

// ---------------------------------------------------------------------------
// K2: per point (one wave each, 4 waves/block), chunk [n0,n1):
//   localized_xyz -> out1 (f32) and LDS
//   WeightNet (3x Linear+BN+ReLU) -> w [16,16]
//   gather feats_x (f32, 2x float4/lane) ; einsum -> nf f32 (chunk-local)
// ---------------------------------------------------------------------------
__global__ __launch_bounds__(256) void k2_point(
    const void* __restrict__ xyz, const int* __restrict__ nei,
    const float* __restrict__ fx,
    const void* __restrict__ W0, const void* __restrict__ g0, const void* __restrict__ b0,
    const void* __restrict__ W1, const void* __restrict__ g1, const void* __restrict__ b1,
    const void* __restrict__ W2, const void* __restrict__ g2, const void* __restrict__ b2,
    float* __restrict__ nf, float* __restrict__ locout, int n0, int n1)
{
  __shared__ float sW0[24], sB0[8], sW1[64], sB1[8], sW2[128], sB2[16];
  __shared__ int   sIdx[4][16];
  __shared__ float sLoc[4][48];
  __shared__ float sHa[4][128];
  __shared__ float sHb[4][128];
  alignas(16) __shared__ float sP[4][256];
  alignas(16) __shared__ float sGF[4][512];

  bool bf = probe_bf16(g0);
  int tid = threadIdx.x;
  if (tid < 24) sW0[tid] = ldf(W0, tid, bf) * ldf(g0, tid & 7, bf);
  else if (tid < 32) sB0[tid - 24] = ldf(b0, tid - 24, bf);
  else if (tid < 96) sW1[tid - 32] = ldf(W1, tid - 32, bf) * ldf(g1, (tid - 32) & 7, bf);
  else if (tid < 104) sB1[tid - 96] = ldf(b1, tid - 96, bf);
  else if (tid < 232) sW2[tid - 104] = ldf(W2, tid - 104, bf) * ldf(g2, (tid - 104) & 15, bf);
  else if (tid < 248) sB2[tid - 232] = ldf(b2, tid - 232, bf);

  int w = tid >> 6, lane = tid & 63;
  int n = n0 + blockIdx.x * 4 + w;
  bool valid = n < n1;

  if (lane < 16) sIdx[w][lane] = valid ? nei[(size_t)n * 16 + lane] : 0;
  __syncthreads();

  // localized xyz: 48 values per point
  if (lane < 48) {
    int k = lane / 3, d = lane - k * 3;
    float v = 0.f;
    if (valid) {
      int m = sIdx[w][k];
      v = ldf(xyz, (size_t)m * 3 + d, bf) - ldf(xyz, (size_t)n * 3 + d, bf);
      locout[(size_t)n * 48 + lane] = v;
    }
    sLoc[w][lane] = v;
  }
  __syncthreads();

  // WeightNet L0: [16,3]@[3,8]+b, relu
#pragma unroll
  for (int r = 0; r < 2; ++r) {
    int o = lane + r * 64;
    int k = o >> 3, j = o & 7;
    float a = sB0[j];
#pragma unroll
    for (int d = 0; d < 3; ++d) a += sLoc[w][k * 3 + d] * sW0[d * 8 + j];
    sHa[w][o] = fmaxf(a, 0.f);
  }
  __syncthreads();
  // L1: [16,8]@[8,8]
#pragma unroll
  for (int r = 0; r < 2; ++r) {
    int o = lane + r * 64;
    int k = o >> 3, j = o & 7;
    float a = sB1[j];
#pragma unroll
    for (int d = 0; d < 8; ++d) a += sHa[w][k * 8 + d] * sW1[d * 8 + j];
    sHb[w][o] = fmaxf(a, 0.f);
  }
  __syncthreads();
  // L2: [16,8]@[8,16] -> sP[k][j]
#pragma unroll
  for (int r = 0; r < 4; ++r) {
    int o = lane + r * 64;
    int k = o >> 4, j = o & 15;
    float a = sB2[j];
#pragma unroll
    for (int d = 0; d < 8; ++d) a += sHb[w][k * 8 + d] * sW2[d * 16 + j];
    sP[w][o] = fmaxf(a, 0.f);
  }

  // gather feats_x: f32, 8 contiguous floats per lane (2x float4)
  {
    int e0 = lane * 8;
    int k = e0 >> 5, c0 = e0 & 31;
    float4 v0 = make_float4(0.f, 0.f, 0.f, 0.f), v1 = v0;
    if (valid) {
      int m = sIdx[w][k];
      const float4* src = reinterpret_cast<const float4*>(fx + (size_t)m * 32 + c0);
      v0 = src[0]; v1 = src[1];
    }
    float4* dst = reinterpret_cast<float4*>(&sGF[w][e0]);
    dst[0] = v0; dst[1] = v1;
  }
  __syncthreads();

  // einsum: new_feat[c*16+m] = sum_k GF[k][c] * P[k][m]
  {
    int c = lane >> 1, mb = (lane & 1) * 8;
    float acc[8] = {0.f, 0.f, 0.f, 0.f, 0.f, 0.f, 0.f, 0.f};
#pragma unroll
    for (int k = 0; k < 16; ++k) {
      float f = sGF[w][k * 32 + c];
      const float4* pw = reinterpret_cast<const float4*>(&sP[w][k * 16 + mb]);
      float4 w0 = pw[0], w1 = pw[1];
      acc[0] += f * w0.x; acc[1] += f * w0.y; acc[2] += f * w0.z; acc[3] += f * w0.w;
      acc[4] += f * w1.x; acc[5] += f * w1.y; acc[6] += f * w1.z; acc[7] += f * w1.w;
    }
    if (valid) {
      float4* dst = reinterpret_cast<float4*>(nf + (size_t)(n - n0) * 512 + (c * 16 + mb));
      dst[0] = make_float4(acc[0], acc[1], acc[2], acc[3]);
      dst[1] = make_float4(acc[4], acc[5], acc[6], acc[7]);
    }
  }
}

// ---------------------------------------------------------------------------
// K3: h = relu(nf [chunk,512] @ (W_lin*g) + b) -> [chunk,64] f32 (chunk-local)
// W_lin in registers; split-K 8 chunks + LDS reduce.
// ---------------------------------------------------------------------------
__global__ __launch_bounds__(256) void k3_lin(
    const float* __restrict__ nf, const void* __restrict__ WL,
    const void* __restrict__ gl, const void* __restrict__ bl,
    float* __restrict__ h, int cnt)
{
  alignas(16) __shared__ float sNF[512];
  __shared__ float sPart[8][64];
  bool bf = probe_bf16(gl);
  int tid = threadIdx.x;
  int jp = tid & 31, kc = tid >> 5;
  int j0 = jp * 2;
  float g0 = ldf(gl, j0, bf), g1 = ldf(gl, j0 + 1, bf);
  float wr0[64], wr1[64];
  if (bf) {
    const u16* WLb = (const u16*)WL;
#pragma unroll
    for (int ii = 0; ii < 64; ++ii) {
      int i = kc * 64 + ii;
      u32 pair = *reinterpret_cast<const u32*>(WLb + (size_t)i * 64 + j0);
      wr0[ii] = bf2f((u16)(pair & 0xFFFFu)) * g0;
      wr1[ii] = bf2f((u16)(pair >> 16)) * g1;
    }
  } else {
    const float* WLf = (const float*)WL;
#pragma unroll
    for (int ii = 0; ii < 64; ++ii) {
      int i = kc * 64 + ii;
      float2 pr = *reinterpret_cast<const float2*>(WLf + (size_t)i * 64 + j0);
      wr0[ii] = pr.x * g0;
      wr1[ii] = pr.y * g1;
    }
  }

  for (int n = blockIdx.x; n < cnt; n += gridDim.x) {
    __syncthreads();  // protect sNF reuse across iterations
    {
      float2 pr = *reinterpret_cast<const float2*>(nf + (size_t)n * 512 + tid * 2);
      sNF[tid * 2]     = pr.x;
      sNF[tid * 2 + 1] = pr.y;
    }
    __syncthreads();
    float a0 = 0.f, a1 = 0.f;
    const float4* p4 = reinterpret_cast<const float4*>(&sNF[kc * 64]);
#pragma unroll
    for (int q = 0; q < 16; ++q) {
      float4 v = p4[q];
      a0 += v.x * wr0[4 * q + 0]; a1 += v.x * wr1[4 * q + 0];
      a0 += v.y * wr0[4 * q + 1]; a1 += v.y * wr1[4 * q + 1];
      a0 += v.z * wr0[4 * q + 2]; a1 += v.z * wr1[4 * q + 2];
      a0 += v.w * wr0[4 * q + 3]; a1 += v.w * wr1[4 * q + 3];
    }
    sPart[kc][j0] = a0;
    sPart[kc][j0 + 1] = a1;
    __syncthreads();
    if (tid < 64) {
      float s = ldf(bl, tid, bf);
#pragma unroll
      for (int q = 0; q < 8; ++q) s += sPart[q][tid];
      h[(size_t)n * 64 + tid] = fmaxf(s, 0.f);
    }
  }
}

// ---------------------------------------------------------------------------
// K4: out = lrelu(h @ (W_u2*g) + feats @ (W_sc*g) + b_u2 + b_sc) -> [N,128] f32
// h chunk-local [cnt,64]; feats/out absolute (offset n0).
// ---------------------------------------------------------------------------
__global__ __launch_bounds__(256) void k4_out(
    const float* __restrict__ h, const void* __restrict__ feats,
    const void* __restrict__ Wu2, const void* __restrict__ gu2, const void* __restrict__ bu2,
    const void* __restrict__ Wsc, const void* __restrict__ gsc, const void* __restrict__ bsc,
    float* __restrict__ out, int n0, int cnt)
{
  alignas(16) __shared__ float sX[128];
  __shared__ float sPart[4][128];
  bool bf = probe_bf16(gu2);
  int tid = threadIdx.x;
  int op = tid & 63, kc = tid >> 6;
  int o0 = op * 2;
  const void* Wsel = (kc < 2) ? Wu2 : Wsc;
  size_t rowoff = (size_t)((kc & 1) * 32) * 128;
  const void* gsel = (kc < 2) ? gu2 : gsc;
  float g0v = ldf(gsel, o0, bf), g1v = ldf(gsel, o0 + 1, bf);
  float wr0[32], wr1[32];
  if (bf) {
    const u16* Wb = (const u16*)Wsel + rowoff;
#pragma unroll
    for (int ii = 0; ii < 32; ++ii) {
      u32 pair = *reinterpret_cast<const u32*>(Wb + (size_t)ii * 128 + o0);
      wr0[ii] = bf2f((u16)(pair & 0xFFFFu)) * g0v;
      wr1[ii] = bf2f((u16)(pair >> 16)) * g1v;
    }
  } else {
    const float* Wf = (const float*)Wsel + rowoff;
#pragma unroll
    for (int ii = 0; ii < 32; ++ii) {
      float2 pr = *reinterpret_cast<const float2*>(Wf + (size_t)ii * 128 + o0);
      wr0[ii] = pr.x * g0v;
      wr1[ii] = pr.y * g1v;
    }
  }

  for (int n = blockIdx.x; n < cnt; n += gridDim.x) {
    __syncthreads();
    if (tid < 64) {
      sX[tid] = h[(size_t)n * 64 + tid];
    } else if (tid < 128) {
      sX[tid] = ldf(feats, (size_t)(n0 + n) * 64 + (tid - 64), bf);
    }
    __syncthreads();
    float a0 = 0.f, a1 = 0.f;
    const float4* p4 = reinterpret_cast<const float4*>(&sX[kc * 32]);
#pragma unroll
    for (int q = 0; q < 8; ++q) {
      float4 v = p4[q];
      a0 += v.x * wr0[4 * q + 0]; a1 += v.x * wr1[4 * q + 0];
      a0 += v.y * wr0[4 * q + 1]; a1 += v.y * wr1[4 * q + 1];
      a0 += v.z * wr0[4 * q + 2]; a1 += v.z * wr1[4 * q + 2];
      a0 += v.w * wr0[4 * q + 3]; a1 += v.w * wr1[4 * q + 3];
    }
    sPart[kc][o0] = a0;
    sPart[kc][o0 + 1] = a1;
    __syncthreads();
    if (tid < 128) {
      float s = ldf(bu2, tid, bf) + ldf(bsc, tid, bf);
      s += sPart[0][tid] + sPart[1][tid] + sPart[2][tid] + sPart[3][tid];
      out[(size_t)(n0 + n) * 128 + tid] = lrelu(s);
    }
  }
}

extern "C" void kernel_launch(void* const* d_in, const int* in_sizes, int n_in,
                              void* d_out, int out_size, void* d_ws, size_t ws_size,
                              hipStream_t stream) {
  const void* xyz   = d_in[0];
  const void* feats = d_in[1];
  const int*  nei   = (const int*)d_in[2];
  const void* W_u1  = d_in[3];
  const void* g_u1  = d_in[4];
  const void* b_u1  = d_in[5];
  const void* W_wn0 = d_in[6];
  const void* g_wn0 = d_in[7];
  const void* b_wn0 = d_in[8];
  const void* W_wn1 = d_in[9];
  const void* g_wn1 = d_in[10];
  const void* b_wn1 = d_in[11];
  const void* W_wn2 = d_in[12];
  const void* g_wn2 = d_in[13];
  const void* b_wn2 = d_in[14];
  const void* W_lin = d_in[15];
  const void* g_lin = d_in[16];
  const void* b_lin = d_in[17];
  const void* W_u2  = d_in[18];
  const void* g_u2  = d_in[19];
  const void* b_u2  = d_in[20];
  const void* W_sc  = d_in[21];
  const void* g_sc  = d_in[22];
  const void* b_sc  = d_in[23];

  int Npts = in_sizes[0] / 3;

  float* out0 = (float*)d_out;                 // [N,128] f32
  float* out1 = out0 + (size_t)Npts * 128;     // [N,16,3] f32

  // Workspace (f32): fx [N,32] global; nf [chunk,512] + hb [chunk,64] chunk-local.
  float* fx = (float*)d_ws;
  size_t fx_bytes = (size_t)Npts * 32 * 4;
  size_t avail = (ws_size > fx_bytes) ? (ws_size - fx_bytes) : 0;
  size_t per_pt = (size_t)(512 + 64) * 4;  // 2304 B/point
  long long cN = (long long)(avail / per_pt);
  if (cN < 1) cN = 1;
  if (cN > Npts) cN = Npts;
  int chunkN = (int)cN;

  float* nf = fx + (size_t)Npts * 32;
  float* hb = nf + (size_t)chunkN * 512;

  k1_unary<<<(Npts + 7) / 8, 256, 0, stream>>>(feats, W_u1, g_u1, b_u1, fx, Npts);

  for (int n0 = 0; n0 < Npts; n0 += chunkN) {
    int n1 = n0 + chunkN;
    if (n1 > Npts) n1 = Npts;
    int cnt = n1 - n0;
    k2_point<<<(cnt + 3) / 4, 256, 0, stream>>>(
        xyz, nei, fx,
        W_wn0, g_wn0, b_wn0, W_wn1, g_wn1, b_wn1, W_wn2, g_wn2, b_wn2,
        nf, out1, n0, n1);
    int g3 = cnt < 768 ? cnt : 768;
    k3_lin<<<g3, 256, 0, stream>>>(nf, W_lin, g_lin, b_lin, hb, cnt);
    k4_out<<<g3, 256, 0, stream>>>(hb, feats, W_u2, g_u2, b_u2,
                                   W_sc, g_sc, b_sc, out0, n0, cnt);
  }
}

// Round 5
// 854.104 us; speedup vs baseline: 1.0222x; 1.0222x over previous
//
#include <hip/hip_runtime.h>
#include <stdint.h>

typedef unsigned short u16;
typedef unsigned int   u32;

// N = 160000, K = 16, C_IN = 64, C1 = 32, C_MID = 16, C2 = 64, C_OUT = 128
// Inputs: float32 (runtime probe retained as insurance). Outputs: float32.

__device__ __forceinline__ float bf2f(u16 h) {
  return __uint_as_float(((u32)h) << 16);
}
__device__ __forceinline__ float lrelu(float x) { return x > 0.f ? x : 0.1f * x; }

__device__ __forceinline__ float ldf(const void* p, size_t i, bool bf) {
  return bf ? bf2f(((const u16*)p)[i]) : ((const float*)p)[i];
}
__device__ __forceinline__ bool probe_bf16(const void* g) {
  return ((*(const u32*)g) & 0xFFFFu) == 0x3F80u;
}

// ---------------------------------------------------------------------------
// K1: feats_x = lrelu(feats @ (W_u1 * g) + b)   [N,64] -> [N,32], f32 out
// ---------------------------------------------------------------------------
__global__ __launch_bounds__(256) void k1_unary(
    const void* __restrict__ feats, const void* __restrict__ W,
    const void* __restrict__ g, const void* __restrict__ b,
    float* __restrict__ fx, int Npts)
{
  __shared__ float sW[64 * 32];
  __shared__ float sb[32];
  __shared__ float sf[8][64];
  bool bf = probe_bf16(g);
  int tid = threadIdx.x;
  for (int e = tid; e < 2048; e += 256) sW[e] = ldf(W, e, bf) * ldf(g, e & 31, bf);
  if (tid < 32) sb[tid] = ldf(b, tid, bf);
  int n0 = blockIdx.x * 8;
  for (int e = tid; e < 512; e += 256) {
    int p = e >> 6, i = e & 63;
    int n = n0 + p;
    sf[p][i] = (n < Npts) ? ldf(feats, (size_t)n * 64 + i, bf) : 0.f;
  }
  __syncthreads();
  int p = tid >> 5, c = tid & 31;
  int n = n0 + p;
  if (n < Npts) {
    float acc = sb[c];
#pragma unroll
    for (int i = 0; i < 64; ++i) acc += sf[p][i] * sW[i * 32 + c];
    fx[(size_t)n * 32 + c] = lrelu(acc);
  }
}

// ---------------------------------------------------------------------------
// K2: per point (one wave each, 4 waves/block), chunk [n0,n1):
//   localized_xyz -> out1 (f32) and LDS; WeightNet -> w[16,16];
//   gather feats_x ; einsum -> nf f32 (chunk-local)
// ---------------------------------------------------------------------------
__global__ __launch_bounds__(256) void k2_point(
    const void* __restrict__ xyz, const int* __restrict__ nei,
    const float* __restrict__ fx,
    const void* __restrict__ W0, const void* __restrict__ g0, const void* __restrict__ b0,
    const void* __restrict__ W1, const void* __restrict__ g1, const void* __restrict__ b1,
    const void* __restrict__ W2, const void* __restrict__ g2, const void* __restrict__ b2,
    float* __restrict__ nf, float* __restrict__ locout, int n0, int n1)
{
  __shared__ float sW0[24], sB0[8], sW1[64], sB1[8], sW2[128], sB2[16];
  __shared__ int   sIdx[4][16];
  __shared__ float sLoc[4][48];
  __shared__ float sHa[4][128];
  __shared__ float sHb[4][128];
  alignas(16) __shared__ float sP[4][256];
  alignas(16) __shared__ float sGF[4][512];

  bool bf = probe_bf16(g0);
  int tid = threadIdx.x;
  if (tid < 24) sW0[tid] = ldf(W0, tid, bf) * ldf(g0, tid & 7, bf);
  else if (tid < 32) sB0[tid - 24] = ldf(b0, tid - 24, bf);
  else if (tid < 96) sW1[tid - 32] = ldf(W1, tid - 32, bf) * ldf(g1, (tid - 32) & 7, bf);
  else if (tid < 104) sB1[tid - 96] = ldf(b1, tid - 96, bf);
  else if (tid < 232) sW2[tid - 104] = ldf(W2, tid - 104, bf) * ldf(g2, (tid - 104) & 15, bf);
  else if (tid < 248) sB2[tid - 232] = ldf(b2, tid - 232, bf);

  int w = tid >> 6, lane = tid & 63;
  int n = n0 + blockIdx.x * 4 + w;
  bool valid = n < n1;

  if (lane < 16) sIdx[w][lane] = valid ? nei[(size_t)n * 16 + lane] : 0;
  __syncthreads();

  if (lane < 48) {
    int k = lane / 3, d = lane - k * 3;
    float v = 0.f;
    if (valid) {
      int m = sIdx[w][k];
      v = ldf(xyz, (size_t)m * 3 + d, bf) - ldf(xyz, (size_t)n * 3 + d, bf);
      locout[(size_t)n * 48 + lane] = v;
    }
    sLoc[w][lane] = v;
  }
  __syncthreads();

#pragma unroll
  for (int r = 0; r < 2; ++r) {
    int o = lane + r * 64;
    int k = o >> 3, j = o & 7;
    float a = sB0[j];
#pragma unroll
    for (int d = 0; d < 3; ++d) a += sLoc[w][k * 3 + d] * sW0[d * 8 + j];
    sHa[w][o] = fmaxf(a, 0.f);
  }
  __syncthreads();
#pragma unroll
  for (int r = 0; r < 2; ++r) {
    int o = lane + r * 64;
    int k = o >> 3, j = o & 7;
    float a = sB1[j];
#pragma unroll
    for (int d = 0; d < 8; ++d) a += sHa[w][k * 8 + d] * sW1[d * 8 + j];
    sHb[w][o] = fmaxf(a, 0.f);
  }
  __syncthreads();
#pragma unroll
  for (int r = 0; r < 4; ++r) {
    int o = lane + r * 64;
    int k = o >> 4, j = o & 15;
    float a = sB2[j];
#pragma unroll
    for (int d = 0; d < 8; ++d) a += sHb[w][k * 8 + d] * sW2[d * 16 + j];
    sP[w][o] = fmaxf(a, 0.f);
  }

  {
    int e0 = lane * 8;
    int k = e0 >> 5, c0 = e0 & 31;
    float4 v0 = make_float4(0.f, 0.f, 0.f, 0.f), v1 = v0;
    if (valid) {
      int m = sIdx[w][k];
      const float4* src = reinterpret_cast<const float4*>(fx + (size_t)m * 32 + c0);
      v0 = src[0]; v1 = src[1];
    }
    float4* dst = reinterpret_cast<float4*>(&sGF[w][e0]);
    dst[0] = v0; dst[1] = v1;
  }
  __syncthreads();

  {
    int c = lane >> 1, mb = (lane & 1) * 8;
    float acc[8] = {0.f, 0.f, 0.f, 0.f, 0.f, 0.f, 0.f, 0.f};
#pragma unroll
    for (int k = 0; k < 16; ++k) {
      float f = sGF[w][k * 32 + c];
      const float4* pw = reinterpret_cast<const float4*>(&sP[w][k * 16 + mb]);
      float4 w0 = pw[0], w1 = pw[1];
      acc[0] += f * w0.x; acc[1] += f * w0.y; acc[2] += f * w0.z; acc[3] += f * w0.w;
      acc[4] += f * w1.x; acc[5] += f * w1.y; acc[6] += f * w1.z; acc[7] += f * w1.w;
    }
    if (valid) {
      float4* dst = reinterpret_cast<float4*>(nf + (size_t)(n - n0) * 512 + (c * 16 + mb));
      dst[0] = make_float4(acc[0], acc[1], acc[2], acc[3]);
      dst[1] = make_float4(acc[4], acc[5], acc[6], acc[7]);
    }
  }
}

// ---------------------------------------------------------------------------
// K3: tiled GEMM  h[cnt,64] = relu(nf[cnt,512] @ (W_lin*g) + b)
// BM=64 BN=64 BK=32, 256 thr, 4x4 acc/thread. A transposed in LDS (stride 68).
// ---------------------------------------------------------------------------
__global__ __launch_bounds__(256) void k3_gemm(
    const float* __restrict__ nf, const void* __restrict__ WL,
    const void* __restrict__ gl, const void* __restrict__ bl,
    float* __restrict__ h, int cnt)
{
  __shared__ float sA[32][68];   // [k][m]
  __shared__ float sB[32][68];   // [k][j], g-folded
  bool bf = probe_bf16(gl);
  int t = threadIdx.x;
  int tx = t & 15, ty = t >> 4;        // cols tx*4..+3, rows ty*4..+3
  int m0 = blockIdx.x * 64;

  float acc[4][4] = {{0.f}};

  for (int kb = 0; kb < 512; kb += 32) {
    // stage A (transposed): thread: row=t>>2 (0..63), k-offset j0=(t&3)*8
    {
      int row = t >> 2, j0 = (t & 3) * 8;
      int m = m0 + row;
      float v[8];
      if (m < cnt) {
        const float4* src = reinterpret_cast<const float4*>(nf + (size_t)m * 512 + kb + j0);
        float4 x0 = src[0], x1 = src[1];
        v[0]=x0.x; v[1]=x0.y; v[2]=x0.z; v[3]=x0.w;
        v[4]=x1.x; v[5]=x1.y; v[6]=x1.z; v[7]=x1.w;
      } else {
#pragma unroll
        for (int q = 0; q < 8; ++q) v[q] = 0.f;
      }
#pragma unroll
      for (int q = 0; q < 8; ++q) sA[j0 + q][row] = v[q];
    }
    // stage B: thread: kk=t>>3 (0..31), j0=(t&7)*8; fold g
    {
      int kk = t >> 3, j0 = (t & 7) * 8;
#pragma unroll
      for (int q = 0; q < 8; ++q) {
        int j = j0 + q;
        sB[kk][j] = ldf(WL, (size_t)(kb + kk) * 64 + j, bf) * ldf(gl, j, bf);
      }
    }
    __syncthreads();
#pragma unroll
    for (int kk = 0; kk < 32; ++kk) {
      float4 a = *reinterpret_cast<const float4*>(&sA[kk][ty * 4]);
      float4 b = *reinterpret_cast<const float4*>(&sB[kk][tx * 4]);
      float av[4] = {a.x, a.y, a.z, a.w};
      float bv[4] = {b.x, b.y, b.z, b.w};
#pragma unroll
      for (int i = 0; i < 4; ++i)
#pragma unroll
        for (int j = 0; j < 4; ++j) acc[i][j] += av[i] * bv[j];
    }
    __syncthreads();
  }

#pragma unroll
  for (int i = 0; i < 4; ++i) {
    int m = m0 + ty * 4 + i;
    if (m < cnt) {
      float4 o;
      float* po = &o.x;
#pragma unroll
      for (int j = 0; j < 4; ++j)
        po[j] = fmaxf(acc[i][j] + ldf(bl, tx * 4 + j, bf), 0.f);
      *reinterpret_cast<float4*>(h + (size_t)m * 64 + tx * 4) = o;
    }
  }
}

// ---------------------------------------------------------------------------
// K4: tiled GEMM  out[cnt,128] = lrelu([h|feats] @ [[Wu2*g];[Wsc*g]] + bu2+bsc)
// BM=64 BN=128 BK=32, 256 thr, 4x8 acc/thread (cols tx*4 and 64+tx*4).
// ---------------------------------------------------------------------------
__global__ __launch_bounds__(256) void k4_gemm(
    const float* __restrict__ h, const void* __restrict__ feats,
    const void* __restrict__ Wu2, const void* __restrict__ gu2, const void* __restrict__ bu2,
    const void* __restrict__ Wsc, const void* __restrict__ gsc, const void* __restrict__ bsc,
    float* __restrict__ out, int n0c, int cnt)
{
  __shared__ float sA[32][68];    // [k][m]
  __shared__ float sB[32][132];   // [k][o], g-folded
  bool bf = probe_bf16(gu2);
  int t = threadIdx.x;
  int tx = t & 15, ty = t >> 4;
  int m0 = blockIdx.x * 64;

  float acc[4][8] = {{0.f}};

  for (int kb = 0; kb < 128; kb += 32) {
    // stage A: k<64 from h (chunk-local), k>=64 from feats (absolute)
    {
      int row = t >> 2, j0 = (t & 3) * 8;
      int m = m0 + row;
      float v[8];
      if (m < cnt) {
        if (kb < 64) {
          const float4* src = reinterpret_cast<const float4*>(h + (size_t)m * 64 + kb + j0);
          float4 x0 = src[0], x1 = src[1];
          v[0]=x0.x; v[1]=x0.y; v[2]=x0.z; v[3]=x0.w;
          v[4]=x1.x; v[5]=x1.y; v[6]=x1.z; v[7]=x1.w;
        } else {
#pragma unroll
          for (int q = 0; q < 8; ++q)
            v[q] = ldf(feats, (size_t)(n0c + m) * 64 + (kb - 64) + j0 + q, bf);
        }
      } else {
#pragma unroll
        for (int q = 0; q < 8; ++q) v[q] = 0.f;
      }
#pragma unroll
      for (int q = 0; q < 8; ++q) sA[j0 + q][row] = v[q];
    }
    // stage B: thread: kk=t>>4 *2 rows? -> use kk=t>>3 (0..31), o0=(t&7)*16
    {
      int kk = t >> 3, o0 = (t & 7) * 16;
      int kg = kb + kk;
      const void* Wsel = (kg < 64) ? Wu2 : Wsc;
      const void* gsel = (kg < 64) ? gu2 : gsc;
      int krow = (kg < 64) ? kg : (kg - 64);
#pragma unroll
      for (int q = 0; q < 16; ++q) {
        int o = o0 + q;
        sB[kk][o] = ldf(Wsel, (size_t)krow * 128 + o, bf) * ldf(gsel, o, bf);
      }
    }
    __syncthreads();
#pragma unroll
    for (int kk = 0; kk < 32; ++kk) {
      float4 a  = *reinterpret_cast<const float4*>(&sA[kk][ty * 4]);
      float4 b0 = *reinterpret_cast<const float4*>(&sB[kk][tx * 4]);
      float4 b1 = *reinterpret_cast<const float4*>(&sB[kk][64 + tx * 4]);
      float av[4] = {a.x, a.y, a.z, a.w};
      float bv[8] = {b0.x, b0.y, b0.z, b0.w, b1.x, b1.y, b1.z, b1.w};
#pragma unroll
      for (int i = 0; i < 4; ++i)
#pragma unroll
        for (int j = 0; j < 8; ++j) acc[i][j] += av[i] * bv[j];
    }
    __syncthreads();
  }

#pragma unroll
  for (int i = 0; i < 4; ++i) {
    int m = m0 + ty * 4 + i;
    if (m < cnt) {
      float4 o0v, o1v;
      float* p0 = &o0v.x; float* p1 = &o1v.x;
#pragma unroll
      for (int j = 0; j < 4; ++j) {
        int c0 = tx * 4 + j, c1 = 64 + tx * 4 + j;
        p0[j] = lrelu(acc[i][j]     + ldf(bu2, c0, bf) + ldf(bsc, c0, bf));
        p1[j] = lrelu(acc[i][4 + j] + ldf(bu2, c1, bf) + ldf(bsc, c1, bf));
      }
      float* orow = out + (size_t)(n0c + m) * 128;
      *reinterpret_cast<float4*>(orow + tx * 4)      = o0v;
      *reinterpret_cast<float4*>(orow + 64 + tx * 4) = o1v;
    }
  }
}

extern "C" void kernel_launch(void* const* d_in, const int* in_sizes, int n_in,
                              void* d_out, int out_size, void* d_ws, size_t ws_size,
                              hipStream_t stream) {
  const void* xyz   = d_in[0];
  const void* feats = d_in[1];
  const int*  nei   = (const int*)d_in[2];
  const void* W_u1  = d_in[3];
  const void* g_u1  = d_in[4];
  const void* b_u1  = d_in[5];
  const void* W_wn0 = d_in[6];
  const void* g_wn0 = d_in[7];
  const void* b_wn0 = d_in[8];
  const void* W_wn1 = d_in[9];
  const void* g_wn1 = d_in[10];
  const void* b_wn1 = d_in[11];
  const void* W_wn2 = d_in[12];
  const void* g_wn2 = d_in[13];
  const void* b_wn2 = d_in[14];
  const void* W_lin = d_in[15];
  const void* g_lin = d_in[16];
  const void* b_lin = d_in[17];
  const void* W_u2  = d_in[18];
  const void* g_u2  = d_in[19];
  const void* b_u2  = d_in[20];
  const void* W_sc  = d_in[21];
  const void* g_sc  = d_in[22];
  const void* b_sc  = d_in[23];

  int Npts = in_sizes[0] / 3;

  float* out0 = (float*)d_out;                 // [N,128] f32
  float* out1 = out0 + (size_t)Npts * 128;     // [N,16,3] f32

  float* fx = (float*)d_ws;
  size_t fx_bytes = (size_t)Npts * 32 * 4;
  size_t avail = (ws_size > fx_bytes) ? (ws_size - fx_bytes) : 0;
  size_t per_pt = (size_t)(512 + 64) * 4;  // 2304 B/point
  long long cN = (long long)(avail / per_pt);
  if (cN < 1) cN = 1;
  if (cN > Npts) cN = Npts;
  int chunkN = (int)cN;

  float* nf = fx + (size_t)Npts * 32;
  float* hb = nf + (size_t)chunkN * 512;

  k1_unary<<<(Npts + 7) / 8, 256, 0, stream>>>(feats, W_u1, g_u1, b_u1, fx, Npts);

  for (int n0 = 0; n0 < Npts; n0 += chunkN) {
    int n1 = n0 + chunkN;
    if (n1 > Npts) n1 = Npts;
    int cnt = n1 - n0;
    k2_point<<<(cnt + 3) / 4, 256, 0, stream>>>(
        xyz, nei, fx,
        W_wn0, g_wn0, b_wn0, W_wn1, g_wn1, b_wn1, W_wn2, g_wn2, b_wn2,
        nf, out1, n0, n1);
    int gB = (cnt + 63) / 64;
    k3_gemm<<<gB, 256, 0, stream>>>(nf, W_lin, g_lin, b_lin, hb, cnt);
    k4_gemm<<<gB, 256, 0, stream>>>(hb, feats, W_u2, g_u2, b_u2,
                                    W_sc, g_sc, b_sc, out0, n0, cnt);
  }
}